// Round 8
// baseline (360.011 us; speedup 1.0000x reference)
//
#include <hip/hip_runtime.h>
#include <hip/hip_bf16.h>

typedef __bf16 bf16_t;
typedef __attribute__((ext_vector_type(8))) __bf16 bf16x8;
typedef __attribute__((ext_vector_type(4))) float f32x4;

#define E_DIM 256
#define J_DIM 32
#define B_DIM 4096
#define M_DIM (B_DIM * J_DIM)
#define BM 128   // memcell rows/block (8 waves x 16 rows)
#define BK 32
#define LDA 40   // bf16: BK + 8 pad (16B-aligned, spreads banks)
#define LDB 40
#define LDAF 33  // fp32: BK + 1 pad (max 2-way bank alias = free)

#define XK_LDA (E_DIM + 4)  // fp32 xk tile pad: 32-way -> 4-way bank alias

// load 8 consecutive fp32, convert to bf16x8 (RNE)
__device__ inline bf16x8 cvt8(const float* __restrict__ p) {
    f32x4 a = *(const f32x4*)p;
    f32x4 b = *(const f32x4*)(p + 4);
    bf16x8 r;
    r[0] = (bf16_t)a[0]; r[1] = (bf16_t)a[1]; r[2] = (bf16_t)a[2]; r[3] = (bf16_t)a[3];
    r[4] = (bf16_t)b[0]; r[5] = (bf16_t)b[1]; r[6] = (bf16_t)b[2]; r[7] = (bf16_t)b[3];
    return r;
}

// ---------------------------------------------------------------------------
// fused: [0,512): xk[b][j] = <x_b, k_j>  (8 b per block, padded LDS)
//        [512,544): vkb[j][f] = bias[f] + sum_e V[f,e]*keys[j,e]
// (unchanged from round 6)
// ---------------------------------------------------------------------------
__global__ __launch_bounds__(256) void xkvkb_kernel(
    const float* __restrict__ x, const float* __restrict__ keys,
    const float* __restrict__ V, const float* __restrict__ bias,
    float* __restrict__ xk, float* __restrict__ vkb) {
    __shared__ float smem[(J_DIM + 8) * XK_LDA];   // 40*260 fp32 = 41.6 KB
    int tid = threadIdx.x, bid = blockIdx.x;
    if (bid < 512) {
        float* sK = smem;                          // [32][XK_LDA]
        float* sX = smem + J_DIM * XK_LDA;         // [8][XK_LDA]
        int b0 = bid * 8;
#pragma unroll
        for (int it = 0; it < 8; ++it) {
            int t = it * 256 + tid;
            int r = t >> 6, c = (t & 63) * 4;
            *(f32x4*)(sK + r * XK_LDA + c) = *(const f32x4*)(keys + (size_t)r * E_DIM + c);
        }
#pragma unroll
        for (int it = 0; it < 2; ++it) {
            int t = it * 256 + tid;
            int r = t >> 6, c = (t & 63) * 4;
            *(f32x4*)(sX + r * XK_LDA + c) =
                *(const f32x4*)(x + (size_t)b0 * E_DIM + (size_t)r * E_DIM + c);
        }
        __syncthreads();
        int j = tid & 31, bl = tid >> 5;
        float acc = 0.f;
        for (int e = 0; e < E_DIM; e += 4) {
            f32x4 xv = *(const f32x4*)(sX + bl * XK_LDA + e);
            f32x4 kv = *(const f32x4*)(sK + j * XK_LDA + e);
#pragma unroll
            for (int i = 0; i < 4; ++i) acc += xv[i] * kv[i];
        }
        xk[(size_t)(b0 + bl) * J_DIM + j] = acc;
    } else {
        int j = bid - 512, f = tid;
        float* sk = smem;
        sk[f] = keys[(size_t)j * E_DIM + f];
        __syncthreads();
        float acc = bias[f];
        for (int e = 0; e < E_DIM; e += 4) {
            f32x4 vv = *(const f32x4*)(V + (size_t)f * E_DIM + e);
#pragma unroll
            for (int i = 0; i < 4; ++i) acc += vv[i] * sk[e + i];
        }
        vkb[(size_t)j * E_DIM + f] = acc;
    }
}

// ---------------------------------------------------------------------------
// wx[b][f] = sum_e W[f,e]*x[b,e] — unchanged from round 6 (well-shaped:
// 256 blocks = 64 m-tiles x 4 n-tiles, 64x64).
// ---------------------------------------------------------------------------
__global__ __launch_bounds__(256) void wx_kernel(const float* __restrict__ x,
                                                 const float* __restrict__ W,
                                                 float* __restrict__ wx) {
    __shared__ __align__(16) bf16_t sA[64][LDA];
    __shared__ __align__(16) bf16_t sBw[64][LDB];
    int tid = threadIdx.x;
    int w = tid >> 6, lane = tid & 63, quad = lane >> 4, l15 = lane & 15;
    int m0 = (blockIdx.x >> 2) * 64, n0 = (blockIdx.x & 3) * 64;
    f32x4 acc[4];
#pragma unroll
    for (int nt = 0; nt < 4; ++nt)
#pragma unroll
        for (int r = 0; r < 4; ++r) acc[nt][r] = 0.f;
    int arow = tid >> 2, akk = (tid & 3) * 8;
    for (int kc = 0; kc < 8; ++kc) {
        int k0 = kc * BK;
        __syncthreads();
        *(bf16x8*)(&sA[arow][akk]) = cvt8(x + (size_t)(m0 + arow) * E_DIM + k0 + akk);
        *(bf16x8*)(&sBw[arow][akk]) = cvt8(W + (size_t)(n0 + arow) * E_DIM + k0 + akk);
        __syncthreads();
        bf16x8 af = *(const bf16x8*)(&sA[w * 16 + l15][quad * 8]);
#pragma unroll
        for (int nt = 0; nt < 4; ++nt) {
            bf16x8 bfr = *(const bf16x8*)(&sBw[nt * 16 + l15][quad * 8]);
            acc[nt] = __builtin_amdgcn_mfma_f32_16x16x32_bf16(af, bfr, acc[nt], 0, 0, 0);
        }
    }
#pragma unroll
    for (int nt = 0; nt < 4; ++nt)
#pragma unroll
        for (int r = 0; r < 4; ++r)
            wx[(size_t)(m0 + w * 16 + quad * 4 + r) * E_DIM + n0 + nt * 16 + l15] =
                acc[nt][r];
}

// ---------------------------------------------------------------------------
// main: EXACT round-0 inner loop, re-tiled to BM=128 / 512 threads (8 waves).
// Per-wave code is byte-identical to the 115-us baseline; per-thread B-stage
// halves (B tile shared by 2x rows); block count halves.
// cand = s@U^T + wx[b] + vkb[j]; gate = sigmoid(<x,s>_fp32 + xk);
// out = normalize(s + gate*relu(cand))
// ---------------------------------------------------------------------------
__global__ __launch_bounds__(512) void memcell_kernel(
    const float* __restrict__ x, const float* __restrict__ state,
    const float* __restrict__ U, const float* __restrict__ wx,
    const float* __restrict__ xk, const float* __restrict__ vkb,
    float* __restrict__ out) {
    __shared__ __align__(16) bf16_t sA[BM][LDA];    // 10.2 KB
    __shared__ __align__(16) bf16_t sB[E_DIM][LDB]; // 20.5 KB
    __shared__ __align__(16) float sAf[BM][LDAF];   // 16.9 KB fp32 state (gate dot)
    __shared__ __align__(16) float sXf[4][E_DIM];   // 4 KB fp32 x rows  (gate dot)
    int tid = threadIdx.x;
    int w = tid >> 6, lane = tid & 63, quad = lane >> 4, l15 = lane & 15;
    int m0 = blockIdx.x * BM;
    int b0 = m0 >> 5;                       // block covers b0 .. b0+3
    f32x4 acc[16];
#pragma unroll
    for (int nt = 0; nt < 16; ++nt)
#pragma unroll
        for (int r = 0; r < 4; ++r) acc[nt][r] = 0.f;
    float gdot = 0.f;
    if (tid < 128) {                         // stage the 4 x-rows (fp32)
        int bb = tid >> 5, p = tid & 31;
        f32x4 xa = *(const f32x4*)(x + (size_t)(b0 + bb) * E_DIM + p * 8);
        f32x4 xb = *(const f32x4*)(x + (size_t)(b0 + bb) * E_DIM + p * 8 + 4);
        *(f32x4*)(&sXf[bb][p * 8]) = xa;
        *(f32x4*)(&sXf[bb][p * 8 + 4]) = xb;
    }
    int arow = tid >> 2, akk = (tid & 3) * 8;   // 512 threads -> 128 rows x 4 slots
    for (int kc = 0; kc < 8; ++kc) {
        int k0 = kc * BK;
        __syncthreads();
        {   // stage state tile: fp32 copy for gate dot + bf16 for MFMA
            const float* sp = state + (size_t)(m0 + arow) * E_DIM + k0 + akk;
            f32x4 a = *(const f32x4*)sp;
            f32x4 b = *(const f32x4*)(sp + 4);
            *(f32x4*)(&sAf[arow][akk]) = a;
            *(f32x4*)(&sAf[arow][akk + 4]) = b;
            bf16x8 r;
            r[0] = (bf16_t)a[0]; r[1] = (bf16_t)a[1]; r[2] = (bf16_t)a[2]; r[3] = (bf16_t)a[3];
            r[4] = (bf16_t)b[0]; r[5] = (bf16_t)b[1]; r[6] = (bf16_t)b[2]; r[7] = (bf16_t)b[3];
            *(bf16x8*)(&sA[arow][akk]) = r;
        }
#pragma unroll
        for (int it = 0; it < 2; ++it) {     // B stage: 1024 slots / 512 threads
            int t = it * 512 + tid;
            int n = t >> 2, kk = (t & 3) * 8;
            *(bf16x8*)(&sB[n][kk]) = cvt8(U + (size_t)n * E_DIM + k0 + kk);
        }
        __syncthreads();
        // A-frag: row = w*16+l15 (wave owns 16 full rows), k = k0 + quad*8 + j
        bf16x8 af = *(const bf16x8*)(&sA[w * 16 + l15][quad * 8]);
#pragma unroll
        for (int i = 0; i < 8; ++i)
            gdot += sAf[w * 16 + l15][quad * 8 + i] * sXf[w >> 1][k0 + quad * 8 + i];
#pragma unroll
        for (int nt = 0; nt < 16; ++nt) {
            bf16x8 bfr = *(const bf16x8*)(&sB[nt * 16 + l15][quad * 8]);
            acc[nt] = __builtin_amdgcn_mfma_f32_16x16x32_bf16(af, bfr, acc[nt], 0, 0, 0);
        }
    }
    // reduce gate dot across quads (k was split quad-wise): lanes sharing l15
    gdot += __shfl_xor(gdot, 16);
    gdot += __shfl_xor(gdot, 32);
    int bw = b0 + (w >> 1);                 // one b per wave pair-half
    float garg = gdot + xk[(size_t)bw * J_DIM + (w & 1) * 16 + l15];
    float gv = 1.f / (1.f + expf(-garg));
    float gate[4];
#pragma unroll
    for (int r = 0; r < 4; ++r) gate[r] = __shfl(gv, quad * 4 + r);
    // epilogue: C/D layout row = quad*4+r, col = nt*16+l15
    float sumsq[4] = {0.f, 0.f, 0.f, 0.f};
    const float* wxrow = wx + (size_t)bw * E_DIM;
#pragma unroll
    for (int nt = 0; nt < 16; ++nt) {
        int f = nt * 16 + l15;
        float wxf = wxrow[f];
#pragma unroll
        for (int r = 0; r < 4; ++r) {
            int rl = quad * 4 + r;
            int jidx = (w & 1) * 16 + rl;
            float c = acc[nt][r] + wxf + vkb[(size_t)jidx * E_DIM + f];
            c = fmaxf(c, 0.f);
            float sv = state[(size_t)(m0 + w * 16 + rl) * E_DIM + f]; // L2-hot re-read
            float t = fmaf(gate[r], c, sv);
            acc[nt][r] = t;
            sumsq[r] += t * t;
        }
    }
    float rn[4];
#pragma unroll
    for (int r = 0; r < 4; ++r) {
        float s2 = sumsq[r];
        s2 += __shfl_xor(s2, 1);
        s2 += __shfl_xor(s2, 2);
        s2 += __shfl_xor(s2, 4);
        s2 += __shfl_xor(s2, 8);
        rn[r] = 1.f / (sqrtf(s2) + 1e-8f);
    }
#pragma unroll
    for (int nt = 0; nt < 16; ++nt)
#pragma unroll
        for (int r = 0; r < 4; ++r)
            out[(size_t)(m0 + w * 16 + quad * 4 + r) * E_DIM + nt * 16 + l15] =
                acc[nt][r] * rn[r];
}

extern "C" void kernel_launch(void* const* d_in, const int* in_sizes, int n_in,
                              void* d_out, int out_size, void* d_ws, size_t ws_size,
                              hipStream_t stream) {
    const float* x     = (const float*)d_in[0];
    const float* state = (const float*)d_in[1];
    const float* keys  = (const float*)d_in[2];
    const float* U     = (const float*)d_in[3];
    const float* V     = (const float*)d_in[4];
    const float* W     = (const float*)d_in[5];
    const float* bias  = (const float*)d_in[6];
    float* out = (float*)d_out;

    float* wsf = (float*)d_ws;
    float* wx  = wsf;                                   // 4096*256 fp32 = 4 MB
    float* xk  = wsf + (size_t)B_DIM * E_DIM;           // 4096*32  fp32 = 512 KB
    float* vkb = xk + (size_t)B_DIM * J_DIM;            // 32*256   fp32 = 32 KB

    xkvkb_kernel<<<544, 256, 0, stream>>>(x, keys, V, bias, xk, vkb);
    wx_kernel<<<256, 256, 0, stream>>>(x, W, wx);
    memcell_kernel<<<M_DIM / BM, 512, 0, stream>>>(x, state, U, wx, xk, vkb, out);
}